// Round 1
// baseline (359.949 us; speedup 1.0000x reference)
//
#include <hip/hip_runtime.h>

// DevConvLayer: dev[i] = max_j ( A[i,j] ? max((s_i - s_j)*wmax_j, (s_i - s_j)*wmin_j) : 0 )
// broadcast across 3 output channels. s = rowsum(x), wmax/wmin = colwise max/min of W_phi.
// Memory-bound on the 256 MiB int32 adjacency read; HBM roofline ~43 us at 6.3 TB/s.
//
// R7: software-pipelined adjacency stream.
//  - Profile forensics: timed window = 1 GiB harness poison fill (~160 us, fixed) +
//    prep (~2 us) + row (~157 us @ only 1.7 TB/s). Row was latency-bound: per
//    iteration the first VALU use waited on in-order vmcnt covering full HBM
//    latency (tables issued AFTER adjacency), and the 64-VGPR cap from
//    __launch_bounds__(256,8) left no room for cross-iteration overlap.
//  - Fix: double-buffer the 4 adjacency loads (issue it+1 before computing it),
//    issue L2-resident table loads FIRST so the compute-entry wait is cheap,
//    __launch_bounds__(256,4) (<=128 VGPR) so the unrolled pipeline fits,
//    and drop the nontemporal hint (zero-reuse stream; nt gains nothing and is
//    the only nonstandard element vs the known-good 6.3 TB/s copy pattern).

#define NN 8192
#define R 4
#define ITERS 8   // (NN/4) / 256 int4-chunks per row

typedef int   iv4 __attribute__((ext_vector_type(4)));
typedef float fv4 __attribute__((ext_vector_type(4)));

// Kernel 1: build fp32 tables s[j], wmax[j], wmin[j] in workspace.
__global__ __launch_bounds__(256) void prep_kernel(
        const float* __restrict__ x,      // [N,3]
        const float* __restrict__ wphi,   // [3,N]
        float* __restrict__ s,
        float* __restrict__ wmax,
        float* __restrict__ wmin) {
    int j = blockIdx.x * blockDim.x + threadIdx.x;
    if (j < NN) {
        s[j] = x[3 * j + 0] + x[3 * j + 1] + x[3 * j + 2];
        float w0 = wphi[0 * NN + j];
        float w1 = wphi[1 * NN + j];
        float w2 = wphi[2 * NN + j];
        wmax[j] = fmaxf(w0, fmaxf(w1, w2));
        wmin[j] = fminf(w0, fminf(w1, w2));
    }
}

// Kernel 2: one block per R=4 rows, 8 pipelined chunks of 1024 j each.
// Running max starts at 0 — faithful, since the reference's candidate set
// always contains 0 (T[i,i]=0, non-neighbors give 0), making the deg>0
// select a no-op.
__global__ __launch_bounds__(256, 4) void row_kernel(
        const int* __restrict__ adj,
        const float* __restrict__ s,
        const float* __restrict__ wmax,
        const float* __restrict__ wmin,
        float* __restrict__ out) {
    const int i0  = blockIdx.x * R;
    const int tid = (int)threadIdx.x;
    const fv4* __restrict__ s4p  = (const fv4*)s;
    const fv4* __restrict__ wx4p = (const fv4*)wmax;
    const fv4* __restrict__ wn4p = (const fv4*)wmin;

    float si[R], m[R];
#pragma unroll
    for (int r = 0; r < R; ++r) { si[r] = s[i0 + r]; m[r] = 0.0f; }

    const iv4* __restrict__ arow = (const iv4*)(adj + (size_t)i0 * NN);

    // Prologue: issue chunk 0's adjacency loads.
    iv4 a_cur[R];
#pragma unroll
    for (int r = 0; r < R; ++r) a_cur[r] = arow[r * (NN / 4) + tid];

#pragma unroll
    for (int it = 0; it < ITERS; ++it) {
        const int j4 = it * 256 + tid;       // int4 index, coalesced across lanes

        // Table loads (L2/L3-resident) issued first: the compute-entry vmcnt
        // wait covers only these + already-arrived a_cur, not the prefetch.
        fv4 sv = s4p[j4];
        fv4 wx = wx4p[j4];
        fv4 wn = wn4p[j4];

        // Prefetch next chunk's adjacency (HBM) — consumed next iteration, so
        // its latency hides under this iteration's compute + next table loads.
        iv4 a_nxt[R];
        if (it + 1 < ITERS) {
            const int j4n = j4 + 256;
#pragma unroll
            for (int r = 0; r < R; ++r) a_nxt[r] = arow[r * (NN / 4) + j4n];
        }

#pragma unroll
        for (int r = 0; r < R; ++r) {
            float d, v;
            d = si[r] - sv.x; v = fmaxf(d * wx.x, d * wn.x); if (a_cur[r].x) m[r] = fmaxf(m[r], v);
            d = si[r] - sv.y; v = fmaxf(d * wx.y, d * wn.y); if (a_cur[r].y) m[r] = fmaxf(m[r], v);
            d = si[r] - sv.z; v = fmaxf(d * wx.z, d * wn.z); if (a_cur[r].z) m[r] = fmaxf(m[r], v);
            d = si[r] - sv.w; v = fmaxf(d * wx.w, d * wn.w); if (a_cur[r].w) m[r] = fmaxf(m[r], v);
        }

        if (it + 1 < ITERS) {
#pragma unroll
            for (int r = 0; r < R; ++r) a_cur[r] = a_nxt[r];
        }
    }

    // Block max-reduction: wave64 shuffle per row, then LDS across the 4 waves.
#pragma unroll
    for (int r = 0; r < R; ++r) {
#pragma unroll
        for (int off = 32; off > 0; off >>= 1)
            m[r] = fmaxf(m[r], __shfl_down(m[r], off, 64));
    }

    __shared__ float red[4][R];
    const int lane = threadIdx.x & 63;
    const int wave = threadIdx.x >> 6;
    if (lane == 0) {
#pragma unroll
        for (int r = 0; r < R; ++r) red[wave][r] = m[r];
    }
    __syncthreads();
    if (threadIdx.x < R) {
        const int r = threadIdx.x;
        float v = fmaxf(fmaxf(red[0][r], red[1][r]), fmaxf(red[2][r], red[3][r]));
        const int i = i0 + r;
        out[3 * i + 0] = v;
        out[3 * i + 1] = v;
        out[3 * i + 2] = v;
    }
}

extern "C" void kernel_launch(void* const* d_in, const int* in_sizes, int n_in,
                              void* d_out, int out_size, void* d_ws, size_t ws_size,
                              hipStream_t stream) {
    const float* x    = (const float*)d_in[0];
    const int*   adj  = (const int*)d_in[1];
    const float* wphi = (const float*)d_in[2];
    // d_in[3] (W_theta) is unused by the reference forward pass.

    float* s    = (float*)d_ws;        // 32 KB
    float* wmax = s + NN;              // 32 KB
    float* wmin = s + 2 * NN;          // 32 KB   (total 96 KB of workspace)

    prep_kernel<<<NN / 256, 256, 0, stream>>>(x, wphi, s, wmax, wmin);
    row_kernel<<<NN / R, 256, 0, stream>>>(adj, s, wmax, wmin, (float*)d_out);
}

// Round 2
// 347.481 us; speedup vs baseline: 1.0359x; 1.0359x over previous
//
#include <hip/hip_runtime.h>

// DevConvLayer: dev[i] = max_j ( A[i,j] ? max((s_i - s_j)*wmax_j, (s_i - s_j)*wmin_j) : 0 )
// broadcast across 3 output channels. s = rowsum(x), wmax/wmin = colwise max/min of W_phi.
// Memory-bound on the 256 MiB int32 adjacency read; HBM roofline ~43 us at 6.3 TB/s.
//
// R8: chunk-phase rotation (channel de-camping). R7's ILP pipeline + occupancy cut
// REGRESSED (+20 us) -> reverted to the R6 structure (nt loads, (256,8), no manual
// pipeline). New theory for the row kernel's ~1.7 TB/s (vs 6.65 TB/s fills in the
// same profile): all 2048 blocks start at chunk it=0, so the whole GPU reads the
// same 4 KB window of every 32 KB row stripe -> addresses confined to 1/8 of the
// space mod 32KB -> only a fraction of HBM channels live at any instant (waves stay
// loosely phase-locked by common latency). Fix: rotate chunk order per block
// (blockIdx & 7). Max-reduce is order-independent -> trivially correct.

#define NN 8192
#define R 4

typedef int   iv4 __attribute__((ext_vector_type(4)));
typedef float fv4 __attribute__((ext_vector_type(4)));

// Kernel 1: build fp32 tables s[j], wmax[j], wmin[j] in workspace.
__global__ __launch_bounds__(256) void prep_kernel(
        const float* __restrict__ x,      // [N,3]
        const float* __restrict__ wphi,   // [3,N]
        float* __restrict__ s,
        float* __restrict__ wmax,
        float* __restrict__ wmin) {
    int j = blockIdx.x * blockDim.x + threadIdx.x;
    if (j < NN) {
        s[j] = x[3 * j + 0] + x[3 * j + 1] + x[3 * j + 2];
        float w0 = wphi[0 * NN + j];
        float w1 = wphi[1 * NN + j];
        float w2 = wphi[2 * NN + j];
        wmax[j] = fmaxf(w0, fmaxf(w1, w2));
        wmin[j] = fminf(w0, fminf(w1, w2));
    }
}

// Kernel 2: one block per R=4 rows. Per chunk of 1024 j: 4 adjacency int4 loads
// (nontemporal, zero-reuse 256 MiB stream, issued first) + 3 table float4 loads
// (L2-resident). Chunk order rotated by blockIdx&7 so all 8 chunk phases (and thus
// all HBM channels) are live simultaneously across the grid. Running max starts at
// 0 — faithful, since the reference's candidate set always contains 0 (T[i,i]=0,
// non-neighbors give 0), making the deg>0 select a no-op.
__global__ __launch_bounds__(256, 8) void row_kernel(
        const int* __restrict__ adj,
        const float* __restrict__ s,
        const float* __restrict__ wmax,
        const float* __restrict__ wmin,
        float* __restrict__ out) {
    const int i0  = blockIdx.x * R;
    const int rot = blockIdx.x & 7;
    const fv4* __restrict__ s4p  = (const fv4*)s;
    const fv4* __restrict__ wx4p = (const fv4*)wmax;
    const fv4* __restrict__ wn4p = (const fv4*)wmin;

    float si[R], m[R];
#pragma unroll
    for (int r = 0; r < R; ++r) { si[r] = s[i0 + r]; m[r] = 0.0f; }

    const iv4* __restrict__ arow = (const iv4*)(adj + (size_t)i0 * NN);

#pragma unroll
    for (int it = 0; it < 8; ++it) {
        const int j4 = (((it + rot) & 7) << 8) + (int)threadIdx.x; // rotated chunk, coalesced
        iv4 a[R];
#pragma unroll
        for (int r = 0; r < R; ++r)
            a[r] = __builtin_nontemporal_load(&arow[r * (NN / 4) + j4]);
        fv4 sv = s4p[j4];
        fv4 wx = wx4p[j4];
        fv4 wn = wn4p[j4];
#pragma unroll
        for (int r = 0; r < R; ++r) {
            float d, v;
            d = si[r] - sv.x; v = fmaxf(d * wx.x, d * wn.x); if (a[r].x) m[r] = fmaxf(m[r], v);
            d = si[r] - sv.y; v = fmaxf(d * wx.y, d * wn.y); if (a[r].y) m[r] = fmaxf(m[r], v);
            d = si[r] - sv.z; v = fmaxf(d * wx.z, d * wn.z); if (a[r].z) m[r] = fmaxf(m[r], v);
            d = si[r] - sv.w; v = fmaxf(d * wx.w, d * wn.w); if (a[r].w) m[r] = fmaxf(m[r], v);
        }
    }

    // Block max-reduction: wave64 shuffle per row, then LDS across the 4 waves.
#pragma unroll
    for (int r = 0; r < R; ++r) {
#pragma unroll
        for (int off = 32; off > 0; off >>= 1)
            m[r] = fmaxf(m[r], __shfl_down(m[r], off, 64));
    }

    __shared__ float red[4][R];
    const int lane = threadIdx.x & 63;
    const int wave = threadIdx.x >> 6;
    if (lane == 0) {
#pragma unroll
        for (int r = 0; r < R; ++r) red[wave][r] = m[r];
    }
    __syncthreads();
    if (threadIdx.x < R) {
        const int r = threadIdx.x;
        float v = fmaxf(fmaxf(red[0][r], red[1][r]), fmaxf(red[2][r], red[3][r]));
        const int i = i0 + r;
        out[3 * i + 0] = v;
        out[3 * i + 1] = v;
        out[3 * i + 2] = v;
    }
}

extern "C" void kernel_launch(void* const* d_in, const int* in_sizes, int n_in,
                              void* d_out, int out_size, void* d_ws, size_t ws_size,
                              hipStream_t stream) {
    const float* x    = (const float*)d_in[0];
    const int*   adj  = (const int*)d_in[1];
    const float* wphi = (const float*)d_in[2];
    // d_in[3] (W_theta) is unused by the reference forward pass.

    float* s    = (float*)d_ws;        // 32 KB
    float* wmax = s + NN;              // 32 KB
    float* wmin = s + 2 * NN;          // 32 KB   (total 96 KB of workspace)

    prep_kernel<<<NN / 256, 256, 0, stream>>>(x, wphi, s, wmax, wmin);
    row_kernel<<<NN / R, 256, 0, stream>>>(adj, s, wmax, wmin, (float*)d_out);
}